// Round 9
// baseline (279.749 us; speedup 1.0000x reference)
//
#include <hip/hip_runtime.h>

typedef __bf16 bf16;
typedef __bf16 bf16x4 __attribute__((ext_vector_type(4)));
typedef __bf16 bf16x8 __attribute__((ext_vector_type(8)));
typedef float f32x4 __attribute__((ext_vector_type(4)));

#define NTOK 49
#define HW 56
#define SHIFT3 3
constexpr float kScale = 0.17677669529663687f;  // 32^-0.5

// ws layout (bytes, 16B aligned)
#define WS_BIAS  0        // f32 [4*49*64]   = 50176 B
#define WS_QKVW  50176    // bf16[49152] packed [ks4][row384][g4][8]
#define WS_PROJW 148480   // bf16[16384] packed [ks4][col128][g4][8]
#define WS_FC1W  181248   // bf16[65536] packed [ks4][col512][g4][8]
#define WS_FC2W  312320   // bf16[65536] packed [ks16][col128][g4][8]

// D[i][j] = sum_k A[i][k]*B[j][k] + C ; lane: A/B row = l&15, k = (l>>4)*8..+8
// D: col j = l&15, row i = (l>>4)*4 + r  (verified by R1-R6 passing kernels)
static __device__ __forceinline__ f32x4 mfma16(bf16x8 a, bf16x8 b, f32x4 c) {
    return __builtin_amdgcn_mfma_f32_16x16x32_bf16(a, b, c, 0, 0, 0);
}

static __device__ __forceinline__ float gelu_f(float x) {
    float x2 = x * x;
    float u2 = x * (1.5957691216f + 0.0713548162f * x2);   // 2u
    return x / (1.0f + __expf(-u2));
}

// ---------------- setup kernels ----------------

__global__ void bias_kernel(const float* __restrict__ rel_table,
                            const int* __restrict__ rel_index,
                            float* __restrict__ biasbuf) {
    int idx = blockIdx.x * 256 + threadIdx.x;     // over 4*49*64 = 12544
    if (idx >= 4 * NTOK * 64) return;
    int j = idx & 63;
    int rest = idx >> 6;
    int i = rest % NTOK;
    int h = rest / NTOK;
    float v = -1e30f;                             // masks j >= 49 (K padding)
    if (j < NTOK) v = rel_table[rel_index[i * NTOK + j] * 4 + h];
    biasbuf[idx] = v;
}

__global__ void wcvt_kernel(const float* __restrict__ qkv_w, const float* __restrict__ proj_w,
                            const float* __restrict__ fc1_w, const float* __restrict__ fc2_w,
                            bf16* __restrict__ qkvwp, bf16* __restrict__ projwp,
                            bf16* __restrict__ fc1wp, bf16* __restrict__ fc2wp) {
    int idx = blockIdx.x * 256 + threadIdx.x;     // 768*256 = 196608 exactly
    if (idx < 49152) {
        int o = idx, e = o & 7, t = o >> 3, g = t & 3; t >>= 2;
        int row = t % 384, ks = t / 384;
        qkvwp[o] = (bf16)qkv_w[row * 128 + ks * 32 + g * 8 + e];
    } else if (idx < 65536) {
        int o = idx - 49152, e = o & 7, t = o >> 3, g = t & 3; t >>= 2;
        int row = t % 128, ks = t / 128;
        projwp[o] = (bf16)proj_w[row * 128 + ks * 32 + g * 8 + e];
    } else if (idx < 131072) {
        int o = idx - 65536, e = o & 7, t = o >> 3, g = t & 3; t >>= 2;
        int row = t % 512, ks = t / 512;
        fc1wp[o] = (bf16)fc1_w[row * 128 + ks * 32 + g * 8 + e];
    } else {
        int o = idx - 131072, e = o & 7, t = o >> 3, g = t & 3; t >>= 2;
        int row = t % 128, ks = t / 128;
        fc2wp[o] = (bf16)fc2_w[row * 512 + ks * 32 + g * 8 + e];
    }
}

// ---------------- fused attention (per-window) ----------------
// block = one 7x7 window; 4 waves = 4 heads.
// LDS 48KB (vT overlays hb, v held in regs across stage1) -> 3 blocks/CU.

__global__ __launch_bounds__(256, 3) void attn_kernel(
    const float* __restrict__ x,
    const float* __restrict__ n1w, const float* __restrict__ n1b,
    const bf16*  __restrict__ qkvwp, const float* __restrict__ qkv_b,
    const bf16*  __restrict__ projwp, const float* __restrict__ proj_b,
    const float* __restrict__ biasbuf,
    float* __restrict__ yout)
{
    __shared__ __align__(16) char smem[49152];
    bf16* const hb = (bf16*)smem;                       // h / vT / ao: [64][128] bf16, 256B rows

    const int tid  = threadIdx.x;
    const int wave = tid >> 6;
    const int lane = tid & 63;
    const int g = lane >> 4;     // 0..3
    const int c = lane & 15;     // 0..15

    char* const qbase  = smem + 16384 + wave * 8192;    // q [64][32] bf16, 64B rows
    char* const kbase  = qbase + 4096;                  // k [64][32]
    char* const pbase  = qbase;                         // P [64][64] 128B rows (overlays q+k)
    char* const vtbase = smem + wave * 4096;            // vT [32][64] 128B rows, OVERLAYS hb

    const int w  = blockIdx.x;
    const int b  = w >> 6;
    const int wi = (w >> 3) & 7;
    const int wj = w & 7;
    const int head = wave;

    // ---- stage 0: LN1 + shifted-window gather -> hb (rows 49..63 zeroed) ----
    {
        const int slot = tid >> 5, l32 = tid & 31;
        for (int it = 0; it < 8; ++it) {
            int t  = slot + (it << 3);                  // 0..63
            int tt = t < NTOK ? t : NTOK - 1;
            int r  = tt / 7, cc = tt - r * 7;
            int row = wi * 7 + r + SHIFT3;  if (row >= HW) row -= HW;
            int col = wj * 7 + cc + SHIFT3; if (col >= HW) col -= HW;
            const float* src = x + (((size_t)(b * 3136 + row * 56 + col)) << 7) + (l32 << 2);
            float4 v = *(const float4*)src;
            float s  = v.x + v.y + v.z + v.w;
            float s2 = v.x * v.x + v.y * v.y + v.z * v.z + v.w * v.w;
            for (int m = 1; m <= 16; m <<= 1) {
                s  += __shfl_xor(s,  m, 64);
                s2 += __shfl_xor(s2, m, 64);
            }
            float mean = s * (1.0f / 128.0f);
            float var  = s2 * (1.0f / 128.0f) - mean * mean;
            float rs   = rsqrtf(var + 1e-5f);
            float4 wv = *(const float4*)(n1w + (l32 << 2));
            float4 bv = *(const float4*)(n1b + (l32 << 2));
            bf16x4 outv;
            if (t < NTOK) {
                outv[0] = (bf16)((v.x - mean) * rs * wv.x + bv.x);
                outv[1] = (bf16)((v.y - mean) * rs * wv.y + bv.y);
                outv[2] = (bf16)((v.z - mean) * rs * wv.z + bv.z);
                outv[3] = (bf16)((v.w - mean) * rs * wv.w + bv.w);
            } else {
                outv[0] = (bf16)0.0f; outv[1] = (bf16)0.0f;
                outv[2] = (bf16)0.0f; outv[3] = (bf16)0.0f;
            }
            int off = (l32 << 3) ^ ((t & 7) << 4);
            *(bf16x4*)((char*)hb + t * 256 + off) = outv;
        }
    }
    __syncthreads();

    // ---- stage 1: qkv. q,k swapped-role; v accumulated into regs (va) ----
    f32x4 fz = {0.f, 0.f, 0.f, 0.f};
    f32x4 va[2][4];                    // carried to after the barrier (static idx)
    #pragma unroll
    for (int nt = 0; nt < 2; ++nt) {
        f32x4 qa[4], ka[4];
        #pragma unroll
        for (int mt = 0; mt < 4; ++mt) { qa[mt] = fz; ka[mt] = fz; va[nt][mt] = fz; }

        #pragma unroll
        for (int ks = 0; ks < 4; ++ks) {
            bf16x8 af[4];
            const int koff = ks * 64 + g * 16;
            #pragma unroll
            for (int mt = 0; mt < 4; ++mt) {
                int row = mt * 16 + c;
                af[mt] = *(const bf16x8*)((char*)hb + row * 256 + (koff ^ ((row & 7) << 4)));
            }
            int jb = head * 32 + nt * 16 + c;
            bf16x8 bq = *(const bf16x8*)(qkvwp + (((ks * 384 + jb) * 4 + g) << 3));
            bf16x8 bk = *(const bf16x8*)(qkvwp + (((ks * 384 + 128 + jb) * 4 + g) << 3));
            bf16x8 bv = *(const bf16x8*)(qkvwp + (((ks * 384 + 256 + jb) * 4 + g) << 3));
            #pragma unroll
            for (int mt = 0; mt < 4; ++mt) {
                qa[mt] = mfma16(bq, af[mt], qa[mt]);        // swapped: A=weight
                ka[mt] = mfma16(bk, af[mt], ka[mt]);        // swapped
                va[nt][mt] = mfma16(af[mt], bv, va[nt][mt]);// original: A=tokens
            }
        }
        // q,k vectorized epilogue (own-wave region, pre-barrier is fine)
        f32x4 qb4 = *(const f32x4*)(qkv_b + head * 32 + nt * 16 + g * 4);
        f32x4 kb4 = *(const f32x4*)(qkv_b + 128 + head * 32 + nt * 16 + g * 4);
        #pragma unroll
        for (int mt = 0; mt < 4; ++mt) {
            int tok = mt * 16 + c;
            bf16x4 qv, kv;
            #pragma unroll
            for (int r = 0; r < 4; ++r) {
                qv[r] = (bf16)(qa[mt][r] + qb4[r]);
                kv[r] = (bf16)(ka[mt][r] + kb4[r]);
            }
            int qoff = (nt * 32 + g * 8) ^ ((tok & 3) << 4);
            *(bf16x4*)(qbase + tok * 64 + qoff) = qv;
            *(bf16x4*)(kbase + tok * 64 + qoff) = kv;
        }
    }
    __syncthreads();   // all waves' h reads done -> hb reusable for vT

    // write vT (from regs) into hb's space (per-wave 4KB slice)
    #pragma unroll
    for (int nt = 0; nt < 2; ++nt) {
        float vb = qkv_b[256 + head * 32 + nt * 16 + c];
        int dl = nt * 16 + c;
        #pragma unroll
        for (int mt = 0; mt < 4; ++mt) {
            bf16x4 vv;
            #pragma unroll
            for (int r = 0; r < 4; ++r) vv[r] = (bf16)(va[nt][mt][r] + vb);
            *(bf16x4*)(vtbase + dl * 128 + ((mt * 32 + g * 8) ^ ((dl & 7) << 4))) = vv;
        }
    }

    // ---- stage 2: S^T tiles: mfma(A=k, B=q) -> lane: qtok=bm*16+c, ktok=bn*16+g*4+r ----
    f32x4 s[4][4];     // [bm][bn]
    #pragma unroll
    for (int bm = 0; bm < 4; ++bm) for (int bn = 0; bn < 4; ++bn) s[bm][bn] = fz;
    {
        bf16x8 aq[4];
        #pragma unroll
        for (int bm = 0; bm < 4; ++bm) {
            int row = bm * 16 + c;
            aq[bm] = *(const bf16x8*)(qbase + row * 64 + ((g * 16) ^ ((row & 3) << 4)));
        }
        #pragma unroll
        for (int bn = 0; bn < 4; ++bn) {
            int row = bn * 16 + c;
            bf16x8 kf = *(const bf16x8*)(kbase + row * 64 + ((g * 16) ^ ((row & 3) << 4)));
            #pragma unroll
            for (int bm = 0; bm < 4; ++bm) s[bm][bn] = mfma16(kf, aq[bm], s[bm][bn]);
        }
    }

    // ---- stage 3: softmax per qtok row ----
    const float* bbase = biasbuf + head * (NTOK * 64);
    float linv[4];
    #pragma unroll
    for (int bm = 0; bm < 4; ++bm) {
        int qt = bm * 16 + c;
        int im = qt < NTOK ? qt : NTOK - 1;
        const float* brow = bbase + im * 64;
        f32x4 vals[4];
        float mx = -3e38f;
        #pragma unroll
        for (int bn = 0; bn < 4; ++bn) {
            f32x4 b4 = *(const f32x4*)(brow + bn * 16 + g * 4);
            #pragma unroll
            for (int r = 0; r < 4; ++r) {
                float v = s[bm][bn][r] * kScale + b4[r];
                vals[bn][r] = v;
                mx = fmaxf(mx, v);
            }
        }
        mx = fmaxf(mx, __shfl_xor(mx, 16, 64));
        mx = fmaxf(mx, __shfl_xor(mx, 32, 64));
        float sum = 0.f;
        #pragma unroll
        for (int bn = 0; bn < 4; ++bn) {
            bf16x4 pv;
            #pragma unroll
            for (int r = 0; r < 4; ++r) {
                float p = __expf(vals[bn][r] - mx);
                sum += p;
                pv[r] = (bf16)p;
            }
            *(bf16x4*)(pbase + qt * 128 + ((bn * 32 + g * 8) ^ ((c & 7) << 4))) = pv;
        }
        sum += __shfl_xor(sum, 16, 64);
        sum += __shfl_xor(sum, 32, 64);
        linv[bm] = 1.0f / sum;
    }

    // ---- stage 4: O^T tiles: mfma(A=vT, B=P) ----
    f32x4 o[4][2];
    #pragma unroll
    for (int mt = 0; mt < 4; ++mt) for (int nt = 0; nt < 2; ++nt) o[mt][nt] = fz;
    #pragma unroll
    for (int ks = 0; ks < 2; ++ks) {
        int koff = ks * 64 + g * 16;
        bf16x8 vf[2], pf[4];
        #pragma unroll
        for (int nt = 0; nt < 2; ++nt)
            vf[nt] = *(const bf16x8*)(vtbase + (nt * 16 + c) * 128 + (koff ^ ((c & 7) << 4)));
        #pragma unroll
        for (int mt = 0; mt < 4; ++mt)
            pf[mt] = *(const bf16x8*)(pbase + (mt * 16 + c) * 128 + (koff ^ ((c & 7) << 4)));
        #pragma unroll
        for (int mt = 0; mt < 4; ++mt)
            #pragma unroll
            for (int nt = 0; nt < 2; ++nt) o[mt][nt] = mfma16(vf[nt], pf[mt], o[mt][nt]);
    }
    __syncthreads();   // ALL waves done reading vT before ao overwrites hb

    // normalize + vector ao write into hb
    #pragma unroll
    for (int mt = 0; mt < 4; ++mt) {
        int qt = mt * 16 + c;
        if (qt < NTOK) {
            float inv = linv[mt];
            #pragma unroll
            for (int nt = 0; nt < 2; ++nt) {
                bf16x4 ov;
                #pragma unroll
                for (int r = 0; r < 4; ++r) ov[r] = (bf16)(o[mt][nt][r] * inv);
                int coff = (head * 64 + nt * 32 + g * 8) ^ ((qt & 7) << 4);
                *(bf16x4*)((char*)hb + qt * 256 + coff) = ov;
            }
        }
    }
    __syncthreads();

    // ---- stage 5: proj swapped (A=weight) + float4 residual scatter ----
    // (rows 49..63 of hb hold stale vT bytes; they only feed masked token cols)
    f32x4 pj[4][2];
    #pragma unroll
    for (int mt = 0; mt < 4; ++mt) for (int nt = 0; nt < 2; ++nt) pj[mt][nt] = fz;
    #pragma unroll
    for (int ks = 0; ks < 4; ++ks) {
        bf16x8 af[4];
        int koff = ks * 64 + g * 16;
        #pragma unroll
        for (int mt = 0; mt < 4; ++mt) {
            int row = mt * 16 + c;
            af[mt] = *(const bf16x8*)((char*)hb + row * 256 + (koff ^ ((row & 7) << 4)));
        }
        #pragma unroll
        for (int nt = 0; nt < 2; ++nt) {
            int colw = wave * 32 + nt * 16 + c;
            bf16x8 bp = *(const bf16x8*)(projwp + (((ks * 128 + colw) * 4 + g) << 3));
            #pragma unroll
            for (int mt = 0; mt < 4; ++mt) pj[mt][nt] = mfma16(bp, af[mt], pj[mt][nt]);
        }
    }
    f32x4 pb0 = *(const f32x4*)(proj_b + wave * 32 + g * 4);
    f32x4 pb1 = *(const f32x4*)(proj_b + wave * 32 + 16 + g * 4);
    #pragma unroll
    for (int mt = 0; mt < 4; ++mt) {
        int qt = mt * 16 + c;
        if (qt < NTOK) {
            int rr = qt / 7, cc = qt - rr * 7;
            int row = wi * 7 + rr + SHIFT3;  if (row >= HW) row -= HW;
            int col = wj * 7 + cc + SHIFT3;  if (col >= HW) col -= HW;
            size_t base = ((size_t)(b * 3136 + row * 56 + col)) << 7;
            int c0 = wave * 32 + g * 4;
            f32x4 x0 = *(const f32x4*)(x + base + c0);
            f32x4 x1 = *(const f32x4*)(x + base + c0 + 16);
            f32x4 y0 = x0 + pj[mt][0] + pb0;
            f32x4 y1 = x1 + pj[mt][1] + pb1;
            *(f32x4*)(yout + base + c0)      = y0;
            *(f32x4*)(yout + base + c0 + 16) = y1;
        }
    }
}

// ---------------- MLP: LN2 -> fc1+gelu -> fc2 -> +residual (in-place) ----------------
// BM=32 tokens/block, 3136 blocks. LDS 32KB (act overlays h2) -> 5 blocks/CU.

__global__ __launch_bounds__(256, 5) void mlp_kernel(
    const float* __restrict__ n2w, const float* __restrict__ n2b,
    const bf16*  __restrict__ fc1wp, const float* __restrict__ fc1_b,
    const bf16*  __restrict__ fc2wp, const float* __restrict__ fc2_b,
    float* __restrict__ y)
{
    __shared__ __align__(16) char smem[32768];
    bf16* const h2    = (bf16*)smem;     // [32][128] bf16, 256B rows (dead after fc1)
    char* const abase = smem;            // act [32][512] bf16, 1024B rows (overlays h2)

    const int tid  = threadIdx.x;
    const int wave = tid >> 6;
    const int lane = tid & 63;
    const int g = lane >> 4;
    const int c = lane & 15;
    const size_t t0 = (size_t)blockIdx.x * 32;

    // LN2 over 32 tokens
    {
        const int slot = tid >> 5, l32 = tid & 31;
        for (int it = 0; it < 4; ++it) {
            int t = slot + (it << 3);                   // 0..31
            const float* src = y + ((t0 + t) << 7) + (l32 << 2);
            float4 v = *(const float4*)src;
            float s  = v.x + v.y + v.z + v.w;
            float s2 = v.x * v.x + v.y * v.y + v.z * v.z + v.w * v.w;
            for (int m = 1; m <= 16; m <<= 1) {
                s  += __shfl_xor(s,  m, 64);
                s2 += __shfl_xor(s2, m, 64);
            }
            float mean = s * (1.0f / 128.0f);
            float var  = s2 * (1.0f / 128.0f) - mean * mean;
            float rs   = rsqrtf(var + 1e-5f);
            float4 wv = *(const float4*)(n2w + (l32 << 2));
            float4 bv = *(const float4*)(n2b + (l32 << 2));
            bf16x4 outv;
            outv[0] = (bf16)((v.x - mean) * rs * wv.x + bv.x);
            outv[1] = (bf16)((v.y - mean) * rs * wv.y + bv.y);
            outv[2] = (bf16)((v.z - mean) * rs * wv.z + bv.z);
            outv[3] = (bf16)((v.w - mean) * rs * wv.w + bv.w);
            int off = (l32 << 3) ^ ((t & 7) << 4);
            *(bf16x4*)((char*)h2 + t * 256 + off) = outv;
        }
    }
    __syncthreads();

    // fc1 swapped (A=weight): wave computes 128 hidden cols x 32 tokens, acc in regs
    f32x4 fz = {0.f, 0.f, 0.f, 0.f};
    f32x4 a1[8][2];   // [nt][mt] : lane holds tok=mt*16+c, hid=nt*16+g*4+r
    #pragma unroll
    for (int nt = 0; nt < 8; ++nt) for (int mt = 0; mt < 2; ++mt) a1[nt][mt] = fz;
    #pragma unroll
    for (int ks = 0; ks < 4; ++ks) {
        bf16x8 af[2];
        int koff = ks * 64 + g * 16;
        #pragma unroll
        for (int mt = 0; mt < 2; ++mt) {
            int row = mt * 16 + c;
            af[mt] = *(const bf16x8*)((char*)h2 + row * 256 + (koff ^ ((row & 7) << 4)));
        }
        #pragma unroll
        for (int nt = 0; nt < 8; ++nt) {
            int col = wave * 128 + nt * 16 + c;
            bf16x8 bw = *(const bf16x8*)(fc1wp + (((ks * 512 + col) * 4 + g) << 3));
            #pragma unroll
            for (int mt = 0; mt < 2; ++mt) a1[nt][mt] = mfma16(bw, af[mt], a1[nt][mt]);
        }
    }
    __syncthreads();   // h2 fully consumed; act may now overlay it

    // gelu + vector act write
    #pragma unroll
    for (int nt = 0; nt < 8; ++nt) {
        f32x4 fb4 = *(const f32x4*)(fc1_b + wave * 128 + nt * 16 + g * 4);
        #pragma unroll
        for (int mt = 0; mt < 2; ++mt) {
            int tok = mt * 16 + c;
            bf16x4 gv;
            #pragma unroll
            for (int r = 0; r < 4; ++r) gv[r] = (bf16)gelu_f(a1[nt][mt][r] + fb4[r]);
            int coff = (wave * 256 + nt * 32 + g * 8) ^ ((tok & 7) << 4);
            *(bf16x4*)(abase + tok * 1024 + coff) = gv;
        }
    }
    __syncthreads();

    // fc2 swapped (A=weight): wave computes 32 out cols; K=512
    f32x4 a2[2][2];   // [nt][mt]
    #pragma unroll
    for (int nt = 0; nt < 2; ++nt) for (int mt = 0; mt < 2; ++mt) a2[nt][mt] = fz;
    #pragma unroll 4
    for (int ks = 0; ks < 16; ++ks) {
        bf16x8 af[2];
        int koff = ks * 64 + g * 16;
        #pragma unroll
        for (int mt = 0; mt < 2; ++mt) {
            int row = mt * 16 + c;
            af[mt] = *(const bf16x8*)(abase + row * 1024 + (koff ^ ((row & 7) << 4)));
        }
        #pragma unroll
        for (int nt = 0; nt < 2; ++nt) {
            int col = wave * 32 + nt * 16 + c;
            bf16x8 bw = *(const bf16x8*)(fc2wp + (((ks * 128 + col) * 4 + g) << 3));
            #pragma unroll
            for (int mt = 0; mt < 2; ++mt) a2[nt][mt] = mfma16(bw, af[mt], a2[nt][mt]);
        }
    }
    // float4 residual epilogue
    #pragma unroll
    for (int nt = 0; nt < 2; ++nt) {
        f32x4 fb4 = *(const f32x4*)(fc2_b + wave * 32 + nt * 16 + g * 4);
        #pragma unroll
        for (int mt = 0; mt < 2; ++mt) {
            size_t idx = ((t0 + mt * 16 + c) << 7) + wave * 32 + nt * 16 + g * 4;
            f32x4 yv = *(const f32x4*)(y + idx);
            yv = yv + a2[nt][mt] + fb4;
            *(f32x4*)(y + idx) = yv;
        }
    }
}

// ---------------- launch ----------------

extern "C" void kernel_launch(void* const* d_in, const int* in_sizes, int n_in,
                              void* d_out, int out_size, void* d_ws, size_t ws_size,
                              hipStream_t stream) {
    const float* x        = (const float*)d_in[0];
    // d_in[1] attn_mask: unused by the reference (faithful)
    const float* n1w      = (const float*)d_in[2];
    const float* n1b      = (const float*)d_in[3];
    const float* qkv_w    = (const float*)d_in[4];
    const float* qkv_b    = (const float*)d_in[5];
    const float* rel_tab  = (const float*)d_in[6];
    const int*   rel_idx  = (const int*)d_in[7];
    const float* proj_w   = (const float*)d_in[8];
    const float* proj_b   = (const float*)d_in[9];
    const float* n2w      = (const float*)d_in[10];
    const float* n2b      = (const float*)d_in[11];
    const float* fc1_w    = (const float*)d_in[12];
    const float* fc1_b    = (const float*)d_in[13];
    const float* fc2_w    = (const float*)d_in[14];
    const float* fc2_b    = (const float*)d_in[15];

    float* yout = (float*)d_out;
    char*  ws   = (char*)d_ws;
    float* biasbuf = (float*)(ws + WS_BIAS);
    bf16*  qkvwp = (bf16*)(ws + WS_QKVW);
    bf16*  projwp= (bf16*)(ws + WS_PROJW);
    bf16*  fc1wp = (bf16*)(ws + WS_FC1W);
    bf16*  fc2wp = (bf16*)(ws + WS_FC2W);

    bias_kernel<<<dim3(49), dim3(256), 0, stream>>>(rel_tab, rel_idx, biasbuf);
    wcvt_kernel<<<dim3(768), dim3(256), 0, stream>>>(qkv_w, proj_w, fc1_w, fc2_w,
                                                     qkvwp, projwp, fc1wp, fc2wp);
    attn_kernel<<<dim3(2048), dim3(256), 0, stream>>>(x, n1w, n1b, qkvwp, qkv_b,
                                                      projwp, proj_b, biasbuf, yout);
    mlp_kernel<<<dim3(3136), dim3(256), 0, stream>>>(n2w, n2b, fc1wp, fc1_b,
                                                     fc2wp, fc2_b, yout);
}

// Round 11
// 242.023 us; speedup vs baseline: 1.1559x; 1.1559x over previous
//
#include <hip/hip_runtime.h>

typedef __bf16 bf16;
typedef __bf16 bf16x4 __attribute__((ext_vector_type(4)));
typedef __bf16 bf16x8 __attribute__((ext_vector_type(8)));
typedef float f32x4 __attribute__((ext_vector_type(4)));

#define NTOK 49
#define HW 56
#define SHIFT3 3
constexpr float kScale = 0.17677669529663687f;  // 32^-0.5

// ws layout (bytes, 16B aligned)
#define WS_BIAS  0        // f32 [4*49*64]   = 50176 B
#define WS_QKVW  50176    // bf16[49152] packed [ks4][row384][g4][8]
#define WS_PROJW 148480   // bf16[16384] packed [ks4][col128][g4][8]
#define WS_FC1W  181248   // bf16[65536] packed [ks4][col512][g4][8]
#define WS_FC2W  312320   // bf16[65536] packed [ks16][col128][g4][8]

// D[i][j] = sum_k A[i][k]*B[j][k] + C ; lane: A/B row = l&15, k = (l>>4)*8..+8
// D: col j = l&15, row i = (l>>4)*4 + r  (verified by R1-R9 passing kernels)
static __device__ __forceinline__ f32x4 mfma16(bf16x8 a, bf16x8 b, f32x4 c) {
    return __builtin_amdgcn_mfma_f32_16x16x32_bf16(a, b, c, 0, 0, 0);
}

static __device__ __forceinline__ float gelu_f(float x) {
    float x2 = x * x;
    float u2 = x * (1.5957691216f + 0.0713548162f * x2);   // 2u
    return x / (1.0f + __expf(-u2));
}

// ---------------- setup kernels ----------------

__global__ void bias_kernel(const float* __restrict__ rel_table,
                            const int* __restrict__ rel_index,
                            float* __restrict__ biasbuf) {
    int idx = blockIdx.x * 256 + threadIdx.x;     // over 4*49*64 = 12544
    if (idx >= 4 * NTOK * 64) return;
    int j = idx & 63;
    int rest = idx >> 6;
    int i = rest % NTOK;
    int h = rest / NTOK;
    float v = -1e30f;                             // masks j >= 49 (K padding)
    if (j < NTOK) v = rel_table[rel_index[i * NTOK + j] * 4 + h];
    biasbuf[idx] = v;
}

__global__ void wcvt_kernel(const float* __restrict__ qkv_w, const float* __restrict__ proj_w,
                            const float* __restrict__ fc1_w, const float* __restrict__ fc2_w,
                            bf16* __restrict__ qkvwp, bf16* __restrict__ projwp,
                            bf16* __restrict__ fc1wp, bf16* __restrict__ fc2wp) {
    int idx = blockIdx.x * 256 + threadIdx.x;     // 768*256 = 196608 exactly
    if (idx < 49152) {
        int o = idx, e = o & 7, t = o >> 3, g = t & 3; t >>= 2;
        int row = t % 384, ks = t / 384;
        qkvwp[o] = (bf16)qkv_w[row * 128 + ks * 32 + g * 8 + e];
    } else if (idx < 65536) {
        int o = idx - 49152, e = o & 7, t = o >> 3, g = t & 3; t >>= 2;
        int row = t % 128, ks = t / 128;
        projwp[o] = (bf16)proj_w[row * 128 + ks * 32 + g * 8 + e];
    } else if (idx < 131072) {
        int o = idx - 65536, e = o & 7, t = o >> 3, g = t & 3; t >>= 2;
        int row = t % 512, ks = t / 512;
        fc1wp[o] = (bf16)fc1_w[row * 128 + ks * 32 + g * 8 + e];
    } else {
        int o = idx - 131072, e = o & 7, t = o >> 3, g = t & 3; t >>= 2;
        int row = t % 128, ks = t / 128;
        fc2wp[o] = (bf16)fc2_w[row * 512 + ks * 32 + g * 8 + e];
    }
}

// ---------------- fully fused block: attn + MLP per window ----------------
// block = one 7x7 window; 4 waves = 4 heads. LDS 48KB -> 3 blocks/CU.
// After stage5, y lives in registers (yreg); LN2+fc1+gelu+fc2 run in-block
// (MLP depends only on this block's 49 tokens). Single final global write.

__global__ __launch_bounds__(256, 3) void attn_mlp_kernel(
    const float* __restrict__ x,
    const float* __restrict__ n1w, const float* __restrict__ n1b,
    const bf16*  __restrict__ qkvwp, const float* __restrict__ qkv_b,
    const bf16*  __restrict__ projwp, const float* __restrict__ proj_b,
    const float* __restrict__ biasbuf,
    const float* __restrict__ n2w, const float* __restrict__ n2b,
    const bf16*  __restrict__ fc1wp, const float* __restrict__ fc1_b,
    const bf16*  __restrict__ fc2wp, const float* __restrict__ fc2_b,
    float* __restrict__ yout)
{
    __shared__ __align__(16) char smem[49152];
    bf16* const hb = (bf16*)smem;                       // h / vT / ao / h2: [64][128] bf16

    const int tid  = threadIdx.x;
    const int wave = tid >> 6;
    const int lane = tid & 63;
    const int g = lane >> 4;     // 0..3
    const int c = lane & 15;     // 0..15

    char* const qbase  = smem + 16384 + wave * 8192;    // q [64][32] bf16, 64B rows
    char* const kbase  = qbase + 4096;                  // k [64][32]
    char* const pbase  = qbase;                         // P [64][64] 128B rows (overlays q+k)
    char* const vtbase = smem + wave * 4096;            // vT [32][64] 128B rows, OVERLAYS hb
    char* const abase  = smem + 16384;                  // mlp: act half [64][256] bf16 (overlays qkP)

    const int w  = blockIdx.x;
    const int b  = w >> 6;
    const int wi = (w >> 3) & 7;
    const int wj = w & 7;
    const int head = wave;

    // ---- stage 0: LN1 + shifted-window gather -> hb (rows 49..63 zeroed) ----
    {
        const int slot = tid >> 5, l32 = tid & 31;
        for (int it = 0; it < 8; ++it) {
            int t  = slot + (it << 3);                  // 0..63
            int tt = t < NTOK ? t : NTOK - 1;
            int r  = tt / 7, cc = tt - r * 7;
            int row = wi * 7 + r + SHIFT3;  if (row >= HW) row -= HW;
            int col = wj * 7 + cc + SHIFT3; if (col >= HW) col -= HW;
            const float* src = x + (((size_t)(b * 3136 + row * 56 + col)) << 7) + (l32 << 2);
            float4 v = *(const float4*)src;
            float s  = v.x + v.y + v.z + v.w;
            float s2 = v.x * v.x + v.y * v.y + v.z * v.z + v.w * v.w;
            for (int m = 1; m <= 16; m <<= 1) {
                s  += __shfl_xor(s,  m, 64);
                s2 += __shfl_xor(s2, m, 64);
            }
            float mean = s * (1.0f / 128.0f);
            float var  = s2 * (1.0f / 128.0f) - mean * mean;
            float rs   = rsqrtf(var + 1e-5f);
            float4 wv = *(const float4*)(n1w + (l32 << 2));
            float4 bv = *(const float4*)(n1b + (l32 << 2));
            bf16x4 outv;
            if (t < NTOK) {
                outv[0] = (bf16)((v.x - mean) * rs * wv.x + bv.x);
                outv[1] = (bf16)((v.y - mean) * rs * wv.y + bv.y);
                outv[2] = (bf16)((v.z - mean) * rs * wv.z + bv.z);
                outv[3] = (bf16)((v.w - mean) * rs * wv.w + bv.w);
            } else {
                outv[0] = (bf16)0.0f; outv[1] = (bf16)0.0f;
                outv[2] = (bf16)0.0f; outv[3] = (bf16)0.0f;
            }
            int off = (l32 << 3) ^ ((t & 7) << 4);
            *(bf16x4*)((char*)hb + t * 256 + off) = outv;
        }
    }
    __syncthreads();                                    // (1) h ready

    // ---- stage 1: qkv. q,k swapped-role; v accumulated into regs ----
    f32x4 fz = {0.f, 0.f, 0.f, 0.f};
    f32x4 va[2][4];
    #pragma unroll
    for (int nt = 0; nt < 2; ++nt) {
        f32x4 qa[4], ka[4];
        #pragma unroll
        for (int mt = 0; mt < 4; ++mt) { qa[mt] = fz; ka[mt] = fz; va[nt][mt] = fz; }

        #pragma unroll
        for (int ks = 0; ks < 4; ++ks) {
            bf16x8 af[4];
            const int koff = ks * 64 + g * 16;
            #pragma unroll
            for (int mt = 0; mt < 4; ++mt) {
                int row = mt * 16 + c;
                af[mt] = *(const bf16x8*)((char*)hb + row * 256 + (koff ^ ((row & 7) << 4)));
            }
            int jb = head * 32 + nt * 16 + c;
            bf16x8 bq = *(const bf16x8*)(qkvwp + (((ks * 384 + jb) * 4 + g) << 3));
            bf16x8 bk = *(const bf16x8*)(qkvwp + (((ks * 384 + 128 + jb) * 4 + g) << 3));
            bf16x8 bv = *(const bf16x8*)(qkvwp + (((ks * 384 + 256 + jb) * 4 + g) << 3));
            #pragma unroll
            for (int mt = 0; mt < 4; ++mt) {
                qa[mt] = mfma16(bq, af[mt], qa[mt]);
                ka[mt] = mfma16(bk, af[mt], ka[mt]);
                va[nt][mt] = mfma16(af[mt], bv, va[nt][mt]);
            }
        }
        f32x4 qb4 = *(const f32x4*)(qkv_b + head * 32 + nt * 16 + g * 4);
        f32x4 kb4 = *(const f32x4*)(qkv_b + 128 + head * 32 + nt * 16 + g * 4);
        #pragma unroll
        for (int mt = 0; mt < 4; ++mt) {
            int tok = mt * 16 + c;
            bf16x4 qv, kv;
            #pragma unroll
            for (int r = 0; r < 4; ++r) {
                qv[r] = (bf16)(qa[mt][r] + qb4[r]);
                kv[r] = (bf16)(ka[mt][r] + kb4[r]);
            }
            int qoff = (nt * 32 + g * 8) ^ ((tok & 3) << 4);
            *(bf16x4*)(qbase + tok * 64 + qoff) = qv;
            *(bf16x4*)(kbase + tok * 64 + qoff) = kv;
        }
    }
    __syncthreads();                                    // (2) h reads done -> vT may overlay

    #pragma unroll
    for (int nt = 0; nt < 2; ++nt) {
        float vb = qkv_b[256 + head * 32 + nt * 16 + c];
        int dl = nt * 16 + c;
        #pragma unroll
        for (int mt = 0; mt < 4; ++mt) {
            bf16x4 vv;
            #pragma unroll
            for (int r = 0; r < 4; ++r) vv[r] = (bf16)(va[nt][mt][r] + vb);
            *(bf16x4*)(vtbase + dl * 128 + ((mt * 32 + g * 8) ^ ((dl & 7) << 4))) = vv;
        }
    }

    // ---- stage 2: S^T tiles: mfma(A=k, B=q) ----
    f32x4 s[4][4];
    #pragma unroll
    for (int bm = 0; bm < 4; ++bm) for (int bn = 0; bn < 4; ++bn) s[bm][bn] = fz;
    {
        bf16x8 aq[4];
        #pragma unroll
        for (int bm = 0; bm < 4; ++bm) {
            int row = bm * 16 + c;
            aq[bm] = *(const bf16x8*)(qbase + row * 64 + ((g * 16) ^ ((row & 3) << 4)));
        }
        #pragma unroll
        for (int bn = 0; bn < 4; ++bn) {
            int row = bn * 16 + c;
            bf16x8 kf = *(const bf16x8*)(kbase + row * 64 + ((g * 16) ^ ((row & 3) << 4)));
            #pragma unroll
            for (int bm = 0; bm < 4; ++bm) s[bm][bn] = mfma16(kf, aq[bm], s[bm][bn]);
        }
    }

    // ---- stage 3: softmax ----
    const float* bbase = biasbuf + head * (NTOK * 64);
    float linv[4];
    #pragma unroll
    for (int bm = 0; bm < 4; ++bm) {
        int qt = bm * 16 + c;
        int im = qt < NTOK ? qt : NTOK - 1;
        const float* brow = bbase + im * 64;
        f32x4 vals[4];
        float mx = -3e38f;
        #pragma unroll
        for (int bn = 0; bn < 4; ++bn) {
            f32x4 b4 = *(const f32x4*)(brow + bn * 16 + g * 4);
            #pragma unroll
            for (int r = 0; r < 4; ++r) {
                float v = s[bm][bn][r] * kScale + b4[r];
                vals[bn][r] = v;
                mx = fmaxf(mx, v);
            }
        }
        mx = fmaxf(mx, __shfl_xor(mx, 16, 64));
        mx = fmaxf(mx, __shfl_xor(mx, 32, 64));
        float sum = 0.f;
        #pragma unroll
        for (int bn = 0; bn < 4; ++bn) {
            bf16x4 pv;
            #pragma unroll
            for (int r = 0; r < 4; ++r) {
                float p = __expf(vals[bn][r] - mx);
                sum += p;
                pv[r] = (bf16)p;
            }
            *(bf16x4*)(pbase + qt * 128 + ((bn * 32 + g * 8) ^ ((c & 7) << 4))) = pv;
        }
        sum += __shfl_xor(sum, 16, 64);
        sum += __shfl_xor(sum, 32, 64);
        linv[bm] = 1.0f / sum;
    }

    // ---- stage 4: O^T tiles: mfma(A=vT, B=P) ----
    f32x4 o[4][2];
    #pragma unroll
    for (int mt = 0; mt < 4; ++mt) for (int nt = 0; nt < 2; ++nt) o[mt][nt] = fz;
    #pragma unroll
    for (int ks = 0; ks < 2; ++ks) {
        int koff = ks * 64 + g * 16;
        bf16x8 vf[2], pf[4];
        #pragma unroll
        for (int nt = 0; nt < 2; ++nt)
            vf[nt] = *(const bf16x8*)(vtbase + (nt * 16 + c) * 128 + (koff ^ ((c & 7) << 4)));
        #pragma unroll
        for (int mt = 0; mt < 4; ++mt)
            pf[mt] = *(const bf16x8*)(pbase + (mt * 16 + c) * 128 + (koff ^ ((c & 7) << 4)));
        #pragma unroll
        for (int mt = 0; mt < 4; ++mt)
            #pragma unroll
            for (int nt = 0; nt < 2; ++nt) o[mt][nt] = mfma16(vf[nt], pf[mt], o[mt][nt]);
    }
    __syncthreads();                                    // (3) vT reads done before ao overwrite

    #pragma unroll
    for (int mt = 0; mt < 4; ++mt) {
        int qt = mt * 16 + c;
        if (qt < NTOK) {
            float inv = linv[mt];
            #pragma unroll
            for (int nt = 0; nt < 2; ++nt) {
                bf16x4 ov;
                #pragma unroll
                for (int r = 0; r < 4; ++r) ov[r] = (bf16)(o[mt][nt][r] * inv);
                int coff = (head * 64 + nt * 32 + g * 8) ^ ((qt & 7) << 4);
                *(bf16x4*)((char*)hb + qt * 256 + coff) = ov;
            }
        }
    }
    __syncthreads();                                    // (4) ao ready

    // ---- stage 5: proj (A=weight); y kept in registers ----
    f32x4 pj[4][2];
    #pragma unroll
    for (int mt = 0; mt < 4; ++mt) for (int nt = 0; nt < 2; ++nt) pj[mt][nt] = fz;
    #pragma unroll
    for (int ks = 0; ks < 4; ++ks) {
        bf16x8 af[4];
        int koff = ks * 64 + g * 16;
        #pragma unroll
        for (int mt = 0; mt < 4; ++mt) {
            int row = mt * 16 + c;
            af[mt] = *(const bf16x8*)((char*)hb + row * 256 + (koff ^ ((row & 7) << 4)));
        }
        #pragma unroll
        for (int nt = 0; nt < 2; ++nt) {
            int colw = wave * 32 + nt * 16 + c;
            bf16x8 bp = *(const bf16x8*)(projwp + (((ks * 128 + colw) * 4 + g) << 3));
            #pragma unroll
            for (int mt = 0; mt < 4; ++mt) pj[mt][nt] = mfma16(bp, af[mt], pj[mt][nt]);
        }
    }
    f32x4 pb0 = *(const f32x4*)(proj_b + wave * 32 + g * 4);
    f32x4 pb1 = *(const f32x4*)(proj_b + wave * 32 + 16 + g * 4);
    f32x4 yreg[4][2];   // y for tok=mt*16+c, ch=wave*32+nt*16+g*4..+4
    #pragma unroll
    for (int mt = 0; mt < 4; ++mt) {
        int qt = mt * 16 + c;
        if (qt < NTOK) {
            int rr = qt / 7, cc = qt - rr * 7;
            int row = wi * 7 + rr + SHIFT3;  if (row >= HW) row -= HW;
            int col = wj * 7 + cc + SHIFT3;  if (col >= HW) col -= HW;
            size_t base = ((size_t)(b * 3136 + row * 56 + col)) << 7;
            int c0 = wave * 32 + g * 4;
            f32x4 x0 = *(const f32x4*)(x + base + c0);
            f32x4 x1 = *(const f32x4*)(x + base + c0 + 16);
            yreg[mt][0] = x0 + pj[mt][0] + pb0;
            yreg[mt][1] = x1 + pj[mt][1] + pb1;
        } else {
            yreg[mt][0] = fz; yreg[mt][1] = fz;
        }
    }

    // ---- MLP phase ----
    // LN2 partial sums: per token (mt,c), reduce this wave's 32 channels
    {
        float* ssum = (float*)(smem + 16384);           // [64][4] f32
        float* ssq  = (float*)(smem + 16384 + 1024);    // [64][4] f32
        float lns[4], lnq[4];
        #pragma unroll
        for (int mt = 0; mt < 4; ++mt) {
            float ps = 0.f, pq = 0.f;
            #pragma unroll
            for (int nt = 0; nt < 2; ++nt)
                #pragma unroll
                for (int r = 0; r < 4; ++r) {
                    float v = yreg[mt][nt][r];
                    ps += v; pq += v * v;
                }
            ps += __shfl_xor(ps, 16, 64);  pq += __shfl_xor(pq, 16, 64);
            ps += __shfl_xor(ps, 32, 64);  pq += __shfl_xor(pq, 32, 64);
            lns[mt] = ps; lnq[mt] = pq;
        }
        if (g == 0) {
            #pragma unroll
            for (int mt = 0; mt < 4; ++mt) {
                int tok = mt * 16 + c;
                ssum[tok * 4 + wave] = lns[mt];
                ssq [tok * 4 + wave] = lnq[mt];
            }
        }
        __syncthreads();                                // (5) lnbuf ready; all hb reads done

        // h2 = LN2(y) -> hb (overlay; all 64 rows written, rows>=49 finite)
        #pragma unroll
        for (int mt = 0; mt < 4; ++mt) {
            int tok = mt * 16 + c;
            f32x4 s4 = *(const f32x4*)(ssum + tok * 4);
            f32x4 q4 = *(const f32x4*)(ssq  + tok * 4);
            float sm = s4[0] + s4[1] + s4[2] + s4[3];
            float sq = q4[0] + q4[1] + q4[2] + q4[3];
            float mean = sm * (1.0f / 128.0f);
            float var  = sq * (1.0f / 128.0f) - mean * mean;
            float rsv  = rsqrtf(var + 1e-5f);
            #pragma unroll
            for (int nt = 0; nt < 2; ++nt) {
                int ch = wave * 32 + nt * 16 + g * 4;
                f32x4 w4 = *(const f32x4*)(n2w + ch);
                f32x4 b4 = *(const f32x4*)(n2b + ch);
                bf16x4 hv;
                #pragma unroll
                for (int r = 0; r < 4; ++r)
                    hv[r] = (bf16)((yreg[mt][nt][r] - mean) * rsv * w4[r] + b4[r]);
                *(bf16x4*)((char*)hb + tok * 256 + ((ch * 2) ^ ((tok & 7) << 4))) = hv;
            }
        }
    }
    __syncthreads();                                    // (6) h2 ready; lnbuf dead

    // fc1/fc2 in two 256-hidden passes; act half [64][256] bf16 overlays qkP
    f32x4 a2acc[2][4];
    #pragma unroll
    for (int nt = 0; nt < 2; ++nt) for (int mt = 0; mt < 4; ++mt) a2acc[nt][mt] = fz;

    #pragma unroll 1
    for (int p = 0; p < 2; ++p) {
        #pragma unroll 1
        for (int sub = 0; sub < 2; ++sub) {             // 32 hidden cols per wave per sub
            f32x4 t1[2][4];
            #pragma unroll
            for (int nt = 0; nt < 2; ++nt) for (int mt = 0; mt < 4; ++mt) t1[nt][mt] = fz;
            #pragma unroll
            for (int ks = 0; ks < 4; ++ks) {
                bf16x8 af[4];
                int koff = ks * 64 + g * 16;
                #pragma unroll
                for (int mt = 0; mt < 4; ++mt) {
                    int row = mt * 16 + c;
                    af[mt] = *(const bf16x8*)((char*)hb + row * 256 + (koff ^ ((row & 7) << 4)));
                }
                #pragma unroll
                for (int nt = 0; nt < 2; ++nt) {
                    int col = p * 256 + wave * 64 + sub * 32 + nt * 16 + c;
                    bf16x8 bw = *(const bf16x8*)(fc1wp + (((ks * 512 + col) * 4 + g) << 3));
                    #pragma unroll
                    for (int mt = 0; mt < 4; ++mt) t1[nt][mt] = mfma16(bw, af[mt], t1[nt][mt]);
                }
            }
            #pragma unroll
            for (int nt = 0; nt < 2; ++nt) {
                f32x4 fb4 = *(const f32x4*)(fc1_b + p * 256 + wave * 64 + sub * 32 + nt * 16 + g * 4);
                int hloc2 = (wave * 64 + sub * 32 + nt * 16 + g * 4) * 2;  // byte off in 512B row
                #pragma unroll
                for (int mt = 0; mt < 4; ++mt) {
                    int tok = mt * 16 + c;
                    bf16x4 gv;
                    #pragma unroll
                    for (int r = 0; r < 4; ++r) gv[r] = (bf16)gelu_f(t1[nt][mt][r] + fb4[r]);
                    *(bf16x4*)(abase + tok * 512 + (hloc2 ^ ((tok & 7) << 4))) = gv;
                }
            }
        }
        __syncthreads();                                // (7/9) act half ready
        #pragma unroll
        for (int ks2 = 0; ks2 < 8; ++ks2) {
            bf16x8 af2[4];
            int koff = ks2 * 64 + g * 16;
            #pragma unroll
            for (int mt = 0; mt < 4; ++mt) {
                int row = mt * 16 + c;
                af2[mt] = *(const bf16x8*)(abase + row * 512 + (koff ^ ((row & 7) << 4)));
            }
            int gks = p * 8 + ks2;
            #pragma unroll
            for (int nt = 0; nt < 2; ++nt) {
                int col = wave * 32 + nt * 16 + c;
                bf16x8 bw = *(const bf16x8*)(fc2wp + (((gks * 128 + col) * 4 + g) << 3));
                #pragma unroll
                for (int mt = 0; mt < 4; ++mt) a2acc[nt][mt] = mfma16(bw, af2[mt], a2acc[nt][mt]);
            }
        }
        __syncthreads();                                // (8/10) act half reusable
    }

    // epilogue: final = y + fc2out + fc2_b (same (tok,ch) layout as yreg)
    #pragma unroll
    for (int mt = 0; mt < 4; ++mt) {
        int qt = mt * 16 + c;
        if (qt < NTOK) {
            int rr = qt / 7, cc = qt - rr * 7;
            int row = wi * 7 + rr + SHIFT3;  if (row >= HW) row -= HW;
            int col = wj * 7 + cc + SHIFT3;  if (col >= HW) col -= HW;
            size_t base = ((size_t)(b * 3136 + row * 56 + col)) << 7;
            #pragma unroll
            for (int nt = 0; nt < 2; ++nt) {
                f32x4 fb4 = *(const f32x4*)(fc2_b + wave * 32 + nt * 16 + g * 4);
                f32x4 out = yreg[mt][nt] + a2acc[nt][mt] + fb4;
                *(f32x4*)(yout + base + wave * 32 + nt * 16 + g * 4) = out;
            }
        }
    }
}

// ---------------- launch ----------------

extern "C" void kernel_launch(void* const* d_in, const int* in_sizes, int n_in,
                              void* d_out, int out_size, void* d_ws, size_t ws_size,
                              hipStream_t stream) {
    const float* x        = (const float*)d_in[0];
    // d_in[1] attn_mask: unused by the reference (faithful)
    const float* n1w      = (const float*)d_in[2];
    const float* n1b      = (const float*)d_in[3];
    const float* qkv_w    = (const float*)d_in[4];
    const float* qkv_b    = (const float*)d_in[5];
    const float* rel_tab  = (const float*)d_in[6];
    const int*   rel_idx  = (const int*)d_in[7];
    const float* proj_w   = (const float*)d_in[8];
    const float* proj_b   = (const float*)d_in[9];
    const float* n2w      = (const float*)d_in[10];
    const float* n2b      = (const float*)d_in[11];
    const float* fc1_w    = (const float*)d_in[12];
    const float* fc1_b    = (const float*)d_in[13];
    const float* fc2_w    = (const float*)d_in[14];
    const float* fc2_b    = (const float*)d_in[15];

    float* yout = (float*)d_out;
    char*  ws   = (char*)d_ws;
    float* biasbuf = (float*)(ws + WS_BIAS);
    bf16*  qkvwp = (bf16*)(ws + WS_QKVW);
    bf16*  projwp= (bf16*)(ws + WS_PROJW);
    bf16*  fc1wp = (bf16*)(ws + WS_FC1W);
    bf16*  fc2wp = (bf16*)(ws + WS_FC2W);

    bias_kernel<<<dim3(49), dim3(256), 0, stream>>>(rel_tab, rel_idx, biasbuf);
    wcvt_kernel<<<dim3(768), dim3(256), 0, stream>>>(qkv_w, proj_w, fc1_w, fc2_w,
                                                     qkvwp, projwp, fc1wp, fc2wp);
    attn_mlp_kernel<<<dim3(2048), dim3(256), 0, stream>>>(
        x, n1w, n1b, qkvwp, qkv_b, projwp, proj_b, biasbuf,
        n2w, n2b, fc1wp, fc1_b, fc2wp, fc2_b, yout);
}